// Round 6
// baseline (266.444 us; speedup 1.0000x reference)
//
#include <hip/hip_runtime.h>

// 7x7 conv, stride 1, pad 3, on 64 x 512 x 512 fp32 (single channel).
// out[n,y,x] = sum_{ky,kx} x[n, y+ky-3, x+kx-3] * w[ky,kx]
//
// R5: LDS-free streaming, ROWS=4 (spill-proof). R4's counters showed ~40% of
// runtime in LDS bank-conflict replays (~23 cyc per ds_read_b128); R3's
// streaming failed only on register spill (32 accs @ VGPR=64). 16 accs fit.

#define IMG_W 512
#define IMG_H 512
#define NIMG  64
#define ROWS  4       // output rows per thread
#define HALO  3

__global__ __launch_bounds__(256, 4) void conv7x7_kernel(
    const float* __restrict__ x,
    const float* __restrict__ wgt,
    float* __restrict__ out)
{
    const int tid = threadIdx.x;
    // 128 threads across x (128*4 = 512 = full row), 2 thread-rows per block.
    const int ox = (tid & 127) * 4;
    const int ty = tid >> 7;
    const int oy = (blockIdx.x * 2 + ty) * ROWS;
    const int n  = blockIdx.y;

    const float* img = x + (size_t)n * (IMG_W * IMG_H);

    // weights: wave-uniform -> SGPRs
    float w[49];
    #pragma unroll
    for (int i = 0; i < 49; ++i) w[i] = wgt[i];

    // x-border predicates (all-or-nothing per aligned float4):
    // left  f4 = cols [ox-4, ox)   -> OOB only when ox == 0
    // right f4 = cols [ox+4, ox+8) -> OOB only when ox == 508
    const bool lval = (ox != 0);
    const bool rval = (ox + 7 < IMG_W);

    float acc[ROWS][4] = {};
    const float4 z4 = make_float4(0.f, 0.f, 0.f, 0.f);

    #pragma unroll
    for (int r = 0; r < ROWS + 2 * HALO; ++r) {   // 10 input rows
        const int gy = oy - HALO + r;
        const bool yv = (unsigned)gy < IMG_H;
        const float* rp = &img[(size_t)gy * IMG_W + ox];
        const float4 a  = (yv && lval) ? *(const float4*)(rp - 4) : z4;
        const float4 b  = yv           ? *(const float4*)(rp)     : z4;
        const float4 c4 = (yv && rval) ? *(const float4*)(rp + 4) : z4;
        // row[t] = input col ox-4+t (t=0..11 contiguous).
        // Output col ox+c, tap kx needs col ox+c+kx-3 -> t = c+kx+1.
        const float row[12] = { a.x, a.y, a.z, a.w,
                                b.x, b.y, b.z, b.w,
                                c4.x, c4.y, c4.z, c4.w };
        #pragma unroll
        for (int j = 0; j < ROWS; ++j) {
            const int ky = r - j;
            if (ky >= 0 && ky < 7) {
                #pragma unroll
                for (int kx = 0; kx < 7; ++kx) {
                    const float wv = w[ky * 7 + kx];
                    #pragma unroll
                    for (int c = 0; c < 4; ++c)
                        acc[j][c] = fmaf(row[c + kx + 1], wv, acc[j][c]);
                }
            }
        }
    }

    float* o = out + (size_t)n * (IMG_W * IMG_H);
    #pragma unroll
    for (int j = 0; j < ROWS; ++j) {
        float4 v = make_float4(acc[j][0], acc[j][1], acc[j][2], acc[j][3]);
        *(float4*)&o[(size_t)(oy + j) * IMG_W + ox] = v;
    }
}

extern "C" void kernel_launch(void* const* d_in, const int* in_sizes, int n_in,
                              void* d_out, int out_size, void* d_ws, size_t ws_size,
                              hipStream_t stream)
{
    const float* x   = (const float*)d_in[0];
    const float* wgt = (const float*)d_in[1];
    float* out       = (float*)d_out;

    // y-strips of 2*4 = 8 rows -> 64 strips; grid = 64 x 64 images
    dim3 grid(IMG_H / (2 * ROWS), NIMG, 1);
    conv7x7_kernel<<<grid, 256, 0, stream>>>(x, wgt, out);
}